// Round 9
// baseline (300.907 us; speedup 1.0000x reference)
//
#include <hip/hip_runtime.h>

#define L_SEQ 4096
#define DM    1024
#define NH    16
#define HD    64

typedef unsigned short ushort_t;
typedef __attribute__((ext_vector_type(8))) short bf16x8;
typedef __attribute__((ext_vector_type(4))) float f32x4;

__device__ inline unsigned short f2bf(float f) {
    union { float f; unsigned int u; } v; v.f = f;
    unsigned int r = v.u + 0x7fffu + ((v.u >> 16) & 1u);
    return (unsigned short)(r >> 16);
}

// async global->LDS, 16B/lane. LDS dest = wave-uniform base + lane*16.
__device__ inline void load_lds16(const ushort_t* g, ushort_t* l) {
    __builtin_amdgcn_global_load_lds(
        (const __attribute__((address_space(1))) unsigned int*)g,
        (__attribute__((address_space(3))) unsigned int*)l, 16, 0, 0);
}

// ---------------------------------------------------------------------------
// Runtime input-dtype detection (bf16 vs fp32 global buffers). Verified R3.
// ---------------------------------------------------------------------------
__device__ inline bool detect_f32(const ushort_t* xraw) {
    __shared__ int s_flag;
    const int t = threadIdx.x;
    if (t < 64) {
        unsigned e = (xraw[2 * t] >> 7) & 0xFFu;
        unsigned long long m = __ballot(e >= 0x88u);
        if (t == 0) s_flag = (__popcll(m) >= 8) ? 1 : 0;
    }
    __syncthreads();
    return s_flag != 0;
}

// ---------------------------------------------------------------------------
// x -> bf16 canonical buffer (4M elems, 8 elems/thread)
// ---------------------------------------------------------------------------
__global__ __launch_bounds__(256) void convert_x(const void* __restrict__ xv,
                                                 ushort_t* __restrict__ xb) {
    bool f32 = detect_f32((const ushort_t*)xv);
    const int i = (blockIdx.x * 256 + threadIdx.x) * 8;
    if (f32) {
        const float* xf = (const float*)xv;
        float4 v0 = *(const float4*)(xf + i);
        float4 v1 = *(const float4*)(xf + i + 4);
        ushort_t pk[8] = {f2bf(v0.x), f2bf(v0.y), f2bf(v0.z), f2bf(v0.w),
                          f2bf(v1.x), f2bf(v1.y), f2bf(v1.z), f2bf(v1.w)};
        *(uint4*)(xb + i) = *(const uint4*)pk;
    } else {
        *(uint4*)(xb + i) = *(const uint4*)((const ushort_t*)xv + i);
    }
}

// ---------------------------------------------------------------------------
// weights -> bf16 TRANSPOSED wT[n][k] (z picks which of 4 weights)
// ---------------------------------------------------------------------------
__global__ __launch_bounds__(256) void convert_wt(const void* __restrict__ xdet,
                                                  const void* __restrict__ w0,
                                                  const void* __restrict__ w1,
                                                  const void* __restrict__ w2,
                                                  const void* __restrict__ w3,
                                                  ushort_t* __restrict__ wT) {
    bool f32 = detect_f32((const ushort_t*)xdet);
    const int z = blockIdx.z;
    const void* w = (z == 0) ? w0 : (z == 1) ? w1 : (z == 2) ? w2 : w3;
    ushort_t* out = wT + (size_t)z * (DM * DM);
    __shared__ ushort_t T[64][65];
    const int k0 = blockIdx.x * 64, n0 = blockIdx.y * 64;
    const int t = threadIdx.x;
    #pragma unroll
    for (int i = 0; i < 16; ++i) {
        int e = t + i * 256;
        int r = e >> 6, c = e & 63;
        T[r][c] = f32 ? f2bf(((const float*)w)[(size_t)(k0 + r) * DM + n0 + c])
                      : ((const ushort_t*)w)[(size_t)(k0 + r) * DM + n0 + c];
    }
    __syncthreads();
    #pragma unroll
    for (int i = 0; i < 16; ++i) {
        int e = t + i * 256;
        int d = e >> 6, l = e & 63;
        out[(size_t)(n0 + d) * DM + k0 + l] = T[l][d];
    }
}

// ---------------------------------------------------------------------------
// m97-structure GEMM: C[M,1024] = A[M,1024] * Bt[1024,1024]^T (Bt is [n][k]).
// 128x128 tile, BK=32, 256 thr. Both operands staged via global_load_lds x16.
// ---------------------------------------------------------------------------
__device__ inline void gemm128_body(const ushort_t* __restrict__ A,
                                    const ushort_t* __restrict__ Bt,
                                    void* __restrict__ Cv, bool c_f32) {
    constexpr int K = 1024, NOUT = 1024;
    __shared__ ushort_t As[128 * 32];
    __shared__ ushort_t Bs[128 * 32];

    const int t = threadIdx.x, lane = t & 63, wave = t >> 6;
    const int l15 = lane & 15, quad = lane >> 4;
    const int m0 = blockIdx.y * 128, n0 = blockIdx.x * 128;
    const int mw = (wave >> 1) * 64, nw = (wave & 1) * 64;
    const int srow = lane >> 2, scol = (lane & 3) * 8;

    f32x4 acc[4][4] = {};

    for (int k0 = 0; k0 < K; k0 += 32) {
        #pragma unroll
        for (int j = 0; j < 2; ++j) {
            const int r0 = wave * 32 + j * 16;
            load_lds16(A  + (size_t)(m0 + r0 + srow) * K + k0 + scol, &As[r0 * 32]);
            load_lds16(Bt + (size_t)(n0 + r0 + srow) * K + k0 + scol, &Bs[r0 * 32]);
        }
        __syncthreads();

        bf16x8 af[4], bf[4];
        #pragma unroll
        for (int i = 0; i < 4; ++i) {
            af[i] = *(const bf16x8*)&As[(mw + i * 16 + l15) * 32 + quad * 8];
            bf[i] = *(const bf16x8*)&Bs[(nw + i * 16 + l15) * 32 + quad * 8];
        }
        #pragma unroll
        for (int mt = 0; mt < 4; ++mt)
            #pragma unroll
            for (int nt = 0; nt < 4; ++nt)
                acc[mt][nt] = __builtin_amdgcn_mfma_f32_16x16x32_bf16(af[mt], bf[nt], acc[mt][nt], 0, 0, 0);

        __syncthreads();
    }

    ushort_t* Ch = (ushort_t*)Cv;
    float*    Cf = (float*)Cv;
    #pragma unroll
    for (int mt = 0; mt < 4; ++mt)
        #pragma unroll
        for (int nt = 0; nt < 4; ++nt)
            #pragma unroll
            for (int r = 0; r < 4; ++r) {
                int row = m0 + mw + mt * 16 + quad * 4 + r;
                int col = n0 + nw + nt * 16 + l15;
                if (c_f32) Cf[(size_t)row * NOUT + col] = acc[mt][nt][r];
                else       Ch[(size_t)row * NOUT + col] = f2bf(acc[mt][nt][r]);
            }
}

__global__ __launch_bounds__(256) void qkv128(const ushort_t* __restrict__ xb,
                                              const ushort_t* __restrict__ wT,
                                              ushort_t* Qp, ushort_t* Kp, ushort_t* Vp) {
    const int z = blockIdx.z;
    const ushort_t* Bt = wT + (size_t)z * (DM * DM);
    ushort_t* C = (z == 0) ? Qp : (z == 1) ? Kp : Vp;
    gemm128_body(xb, Bt, C, false);
}

__global__ __launch_bounds__(256) void ogemm128(const void* __restrict__ xdet,
                                                const ushort_t* __restrict__ An,
                                                const ushort_t* __restrict__ woT,
                                                void* __restrict__ C) {
    bool f32 = detect_f32((const ushort_t*)xdet);
    gemm128_body(An, woT, C, f32);
}

// ---------------------------------------------------------------------------
// V transpose: Vp[L][DM] -> Vt[DM][L]
// ---------------------------------------------------------------------------
__global__ __launch_bounds__(256) void transpose_kernel(const ushort_t* __restrict__ Vp,
                                                        ushort_t* __restrict__ Vt) {
    __shared__ ushort_t T[64][65];
    const int l0 = blockIdx.x * 64, d0 = blockIdx.y * 64;
    const int t  = threadIdx.x;
    #pragma unroll
    for (int i = 0; i < 16; ++i) {
        int e = t + i * 256;
        int r = e >> 6, c = e & 63;
        T[r][c] = Vp[(size_t)(l0 + r) * DM + d0 + c];
    }
    __syncthreads();
    #pragma unroll
    for (int i = 0; i < 16; ++i) {
        int e = t + i * 256;
        int d = e >> 6, l = e & 63;
        Vt[(size_t)(d0 + d) * L_SEQ + l0 + l] = T[l][d];
    }
}

// ---------------------------------------------------------------------------
// Flash attention, S^T formulation. R8 base (XCD-local head decode, async
// glds staging with XOR swizzle, R5 online softmax, paired uniform blocks)
// + R9: DOUBLE-BUFFERED K/V staging, ONE barrier per stage:
//   [barrier: buf[par] ready] -> issue glds for stage ss+1 into buf[par^1]
//   -> compute stage ss from buf[par].
// The compiler's vmcnt(0)-before-s_barrier drain now lands AFTER the loads
// had the whole compute phase to complete -> exposed latency ~0. Cross-half
// pipelining: half0's last stage prefetches half1's stage 0 (same head).
// LDS = 2x16(K) + 2x16(V) + 16(Pt, XOR-swizzled unpadded) = 80 KB exactly
// -> 2 blocks/CU preserved.
// ---------------------------------------------------------------------------
__global__ __launch_bounds__(256) void attn_kernel(const ushort_t* __restrict__ Q,
                                                   const ushort_t* __restrict__ Kp,
                                                   const ushort_t* __restrict__ Vt,
                                                   ushort_t* __restrict__ O) {
    __shared__ ushort_t Ks[2][128 * 64];   // [kv][d], swizzled, 2 x 16 KB
    __shared__ ushort_t Vs[2][64 * 128];   // [d][kv], swizzled, 2 x 16 KB
    __shared__ ushort_t Pt[64 * 128];      // [q][kv], swizzled,     16 KB

    const int b    = blockIdx.x;               // 0..511
    const int h    = 2 * (b & 7) + ((b >> 3) & 1);
    const int bx   = b >> 4;                   // 0..31
    const int t    = threadIdx.x;
    const int lane = t & 63, wave = t >> 6;
    const int l15  = lane & 15, quad = lane >> 4;
    const float LOG2E  = 1.44269504f;
    const float slope2 = exp2f(-0.5f * (float)(h + 1)) * LOG2E;
    const float c0     = 0.125f * LOG2E;
    const float qd4f   = (float)(quad * 4);

    // staging lane constants
    const int krow = lane >> 3, kgr = (lane & 7) ^ (lane >> 3);      // K slab
    const int vsub = lane >> 4;                                       // V slab
    // fragment-read swizzle (loop-invariant)
    const int swz = l15 & 7;

    // issue one stage's K+V loads into buffer `buf` (all 4 waves cooperate)
    auto stage_load = [&](int buf, int kv0) {
        #pragma unroll
        for (int i = 0; i < 4; ++i) {
            const int j = wave * 4 + i;
            const int r = 8 * j + krow;
            load_lds16(Kp + (size_t)(kv0 + r) * DM + h * HD + kgr * 8,
                       &Ks[buf][8 * j * 64]);
        }
        #pragma unroll
        for (int i = 0; i < 4; ++i) {
            const int j = wave * 4 + i;
            const int d = 4 * j + vsub;
            const int g = (lane & 15) ^ (4 * (j & 1) + vsub);
            load_lds16(Vt + (size_t)(h * HD + d) * L_SEQ + kv0 + g * 8,
                       &Vs[buf][4 * j * 128]);
        }
    };

    int par = 0;
    stage_load(0, 0);   // prologue: (half 0, s 0) -> buf 0

    #pragma unroll
    for (int half = 0; half < 2; ++half) {
        const int qb = half ? bx : (63 - bx);
        const int q0 = qb * 64;
        const int qg = q0 + wave * 16 + l15;   // this lane's query row
        const float qf = (float)qg;

        bf16x8 bq[2];
        #pragma unroll
        for (int kt = 0; kt < 2; ++kt)
            bq[kt] = *(const bf16x8*)(Q + (size_t)qg * DM + h * HD + kt * 32 + quad * 8);

        f32x4 acc_o[4] = {};
        float m2 = -1e30f, l_r = 0.f;

        const int nst = (qb + 2) >> 1;
        for (int s = 0; s < nst; ++s) {
            const int kv0 = s * 128;
            __syncthreads();   // buf[par] fully staged (drain is ~free: loads
                               // were issued one full compute phase ago)

            // prefetch next stage (or next half's stage 0) into buf[par^1]
            const int nkv0 = (s + 1 < nst) ? (s + 1) * 128 : 0;
            stage_load(par ^ 1, nkv0);

            // S^T[kv][q]: A = K (m=kv), B = Q (n=q). Lane: q=l15, kv=mt*16+quad*4+r
            f32x4 sacc[8];
            #pragma unroll
            for (int mt = 0; mt < 8; ++mt) sacc[mt] = (f32x4){0.f, 0.f, 0.f, 0.f};
            #pragma unroll
            for (int kt = 0; kt < 2; ++kt)
                #pragma unroll
                for (int mt = 0; mt < 8; ++mt) {
                    bf16x8 a = *(const bf16x8*)&Ks[par][(mt * 16 + l15) * 64
                                                        + (((kt * 4 + quad) ^ swz) * 8)];
                    sacc[mt] = __builtin_amdgcn_mfma_f32_16x16x32_bf16(a, bq[kt], sacc[mt], 0, 0, 0);
                }

            // scores: /sqrt(hd) + alibi (log2 domain), causal mask on diag stage
            const bool diag = (kv0 + 128 > q0);
            const float off = slope2 * ((float)kv0 + qd4f - qf);
            #pragma unroll
            for (int mt = 0; mt < 8; ++mt)
                #pragma unroll
                for (int r = 0; r < 4; ++r) {
                    float kvl = (float)(mt * 16 + r);
                    float s2  = fmaf(sacc[mt][r], c0, fmaf(slope2, kvl, off));
                    if (diag) {
                        int kvg = kv0 + mt * 16 + quad * 4 + r;
                        s2 = (kvg <= qg) ? s2 : -1e30f;
                    }
                    sacc[mt][r] = s2;
                }

            // online softmax: in-register row max + quad-combine
            float mx = sacc[0][0];
            #pragma unroll
            for (int mt = 0; mt < 8; ++mt)
                #pragma unroll
                for (int r = 0; r < 4; ++r) mx = fmaxf(mx, sacc[mt][r]);
            mx = fmaxf(mx, __shfl_xor(mx, 16));
            mx = fmaxf(mx, __shfl_xor(mx, 32));
            float m_new = fmaxf(m2, mx);
            float alpha = exp2f(m2 - m_new);
            m2 = m_new;

            float rs = 0.f;
            #pragma unroll
            for (int mt = 0; mt < 8; ++mt)
                #pragma unroll
                for (int r = 0; r < 4; ++r) {
                    float p = exp2f(sacc[mt][r] - m2);
                    sacc[mt][r] = p;
                    rs += p;
                }
            rs += __shfl_xor(rs, 16);
            rs += __shfl_xor(rs, 32);
            l_r = l_r * alpha + rs;

            float alpha_row[4];
            #pragma unroll
            for (int r = 0; r < 4; ++r) alpha_row[r] = __shfl(alpha, quad * 4 + r);
            #pragma unroll
            for (int nt = 0; nt < 4; ++nt)
                #pragma unroll
                for (int r = 0; r < 4; ++r) acc_o[nt][r] *= alpha_row[r];

            // pack P^T -> Pt[q][kv] (b64 truncation pack, XOR-swizzled rows;
            // row&7 == l15&7 so the write/read swizzle agree)
            #pragma unroll
            for (int mt = 0; mt < 8; ++mt) {
                union { float f; unsigned u; } a0, a1, a2, a3;
                a0.f = sacc[mt][0]; a1.f = sacc[mt][1];
                a2.f = sacc[mt][2]; a3.f = sacc[mt][3];
                uint2 w;
                w.x = __builtin_amdgcn_perm(a1.u, a0.u, 0x07060302);
                w.y = __builtin_amdgcn_perm(a3.u, a2.u, 0x07060302);
                const int g = mt * 2 + (quad >> 1);
                *(uint2*)&Pt[(wave * 16 + l15) * 128
                             + ((g ^ swz) * 8 + (quad & 1) * 4)] = w;
            }
            __threadfence_block();   // wave-private Pt rows: order writes/reads

            // O += P·V: A = Pt[q][kv] (swizzled), B = Vs[d][kv] (swizzled)
            #pragma unroll
            for (int kt = 0; kt < 4; ++kt) {
                bf16x8 a = *(const bf16x8*)&Pt[(wave * 16 + l15) * 128
                                               + (((kt * 4 + quad) ^ swz) * 8)];
                #pragma unroll
                for (int nt = 0; nt < 4; ++nt) {
                    bf16x8 bvv = *(const bf16x8*)&Vs[par][(nt * 16 + l15) * 128
                                                          + (((kt * 4 + quad) ^ swz) * 8)];
                    acc_o[nt] = __builtin_amdgcn_mfma_f32_16x16x32_bf16(a, bvv, acc_o[nt], 0, 0, 0);
                }
            }

            par ^= 1;
        }

        // epilogue (per half)
        float linv[4];
        #pragma unroll
        for (int r = 0; r < 4; ++r) linv[r] = 1.0f / __shfl(l_r, quad * 4 + r);
        #pragma unroll
        for (int nt = 0; nt < 4; ++nt)
            #pragma unroll
            for (int r = 0; r < 4; ++r) {
                int row = q0 + wave * 16 + quad * 4 + r;
                O[(size_t)row * DM + h * HD + nt * 16 + l15] = f2bf(acc_o[nt][r] * linv[r]);
            }
    }
}

// ---------------------------------------------------------------------------
extern "C" void kernel_launch(void* const* d_in, const int* in_sizes, int n_in,
                              void* d_out, int out_size, void* d_ws, size_t ws_size,
                              hipStream_t stream) {
    const void* x  = d_in[0];
    const void* wq = d_in[1];
    const void* wk = d_in[2];
    const void* wv = d_in[3];
    const void* wo = d_in[4];

    const size_t SZ = (size_t)L_SEQ * DM;   // 4M elems
    const size_t WZ = (size_t)DM * DM;      // 1M elems
    ushort_t* xb = (ushort_t*)d_ws;         // 8 MB
    ushort_t* wT = xb + SZ;                 // 4 x 2 MB
    ushort_t* Qp = wT + 4 * WZ;             // 8 MB
    ushort_t* Kp = Qp + SZ;                 // 8 MB
    ushort_t* Vp = Kp + SZ;                 // 8 MB
    ushort_t* Vt = Vp + SZ;                 // 8 MB  -> total 48 MB
    ushort_t* An = xb;                      // xb dead after qkv -> safe alias

    convert_x<<<2048, 256, 0, stream>>>(x, xb);
    convert_wt<<<dim3(16, 16, 4), 256, 0, stream>>>(x, wq, wk, wv, wo, wT);
    qkv128<<<dim3(DM / 128, L_SEQ / 128, 3), 256, 0, stream>>>(xb, wT, Qp, Kp, Vp);
    transpose_kernel<<<dim3(L_SEQ / 64, DM / 64), 256, 0, stream>>>(Vp, Vt);
    attn_kernel<<<512, 256, 0, stream>>>(Qp, Kp, Vt, An);
    ogemm128<<<dim3(DM / 128, L_SEQ / 128), 256, 0, stream>>>(x, An, wT + 3 * WZ, d_out);
}

// Round 10
// 280.963 us; speedup vs baseline: 1.0710x; 1.0710x over previous
//
#include <hip/hip_runtime.h>

#define L_SEQ 4096
#define DM    1024
#define NH    16
#define HD    64

typedef unsigned short ushort_t;
typedef __attribute__((ext_vector_type(8))) short bf16x8;
typedef __attribute__((ext_vector_type(4))) float f32x4;

__device__ inline unsigned short f2bf(float f) {
    union { float f; unsigned int u; } v; v.f = f;
    unsigned int r = v.u + 0x7fffu + ((v.u >> 16) & 1u);
    return (unsigned short)(r >> 16);
}

// async global->LDS, 16B/lane. LDS dest = wave-uniform base + lane*16.
__device__ inline void load_lds16(const ushort_t* g, ushort_t* l) {
    __builtin_amdgcn_global_load_lds(
        (const __attribute__((address_space(1))) unsigned int*)g,
        (__attribute__((address_space(3))) unsigned int*)l, 16, 0, 0);
}

// ---------------------------------------------------------------------------
// Runtime input-dtype detection (bf16 vs fp32 global buffers). Verified R3.
// ---------------------------------------------------------------------------
__device__ inline bool detect_f32(const ushort_t* xraw) {
    __shared__ int s_flag;
    const int t = threadIdx.x;
    if (t < 64) {
        unsigned e = (xraw[2 * t] >> 7) & 0xFFu;
        unsigned long long m = __ballot(e >= 0x88u);
        if (t == 0) s_flag = (__popcll(m) >= 8) ? 1 : 0;
    }
    __syncthreads();
    return s_flag != 0;
}

// ---------------------------------------------------------------------------
// Fused converts: z=0..3 -> weight z transposed bf16 wT[n][k]; z=4 -> x bf16.
// grid (16,16,5) x 256 thr.
// ---------------------------------------------------------------------------
__global__ __launch_bounds__(256) void convert_all(const void* __restrict__ xv,
                                                   const void* __restrict__ w0,
                                                   const void* __restrict__ w1,
                                                   const void* __restrict__ w2,
                                                   const void* __restrict__ w3,
                                                   ushort_t* __restrict__ xb,
                                                   ushort_t* __restrict__ wT) {
    bool f32 = detect_f32((const ushort_t*)xv);
    const int z = blockIdx.z;
    const int t = threadIdx.x;

    if (z == 4) {
        // x: 4M elems; 256 blocks x 8 iters x 256 thr x 8 elems
        const int B0 = (blockIdx.y * 16 + blockIdx.x) * 16384;
        #pragma unroll
        for (int it = 0; it < 8; ++it) {
            const int i = B0 + it * 2048 + t * 8;
            if (f32) {
                const float* xf = (const float*)xv;
                float4 v0 = *(const float4*)(xf + i);
                float4 v1 = *(const float4*)(xf + i + 4);
                ushort_t pk[8] = {f2bf(v0.x), f2bf(v0.y), f2bf(v0.z), f2bf(v0.w),
                                  f2bf(v1.x), f2bf(v1.y), f2bf(v1.z), f2bf(v1.w)};
                *(uint4*)(xb + i) = *(const uint4*)pk;
            } else {
                *(uint4*)(xb + i) = *(const uint4*)((const ushort_t*)xv + i);
            }
        }
        return;
    }

    const void* w = (z == 0) ? w0 : (z == 1) ? w1 : (z == 2) ? w2 : w3;
    ushort_t* out = wT + (size_t)z * (DM * DM);
    __shared__ ushort_t T[64][65];
    const int k0 = blockIdx.x * 64, n0 = blockIdx.y * 64;
    #pragma unroll
    for (int i = 0; i < 16; ++i) {
        int e = t + i * 256;
        int r = e >> 6, c = e & 63;
        T[r][c] = f32 ? f2bf(((const float*)w)[(size_t)(k0 + r) * DM + n0 + c])
                      : ((const ushort_t*)w)[(size_t)(k0 + r) * DM + n0 + c];
    }
    __syncthreads();
    #pragma unroll
    for (int i = 0; i < 16; ++i) {
        int e = t + i * 256;
        int d = e >> 6, l = e & 63;
        out[(size_t)(n0 + d) * DM + k0 + l] = T[l][d];
    }
}

// ---------------------------------------------------------------------------
// BK=64 GEMM: C[128,128] tile of A[M,1024] * Bt[1024,1024]^T (Bt is [n][k]).
// 16 k-iters x 32 MFMA (half the barriers of BK=32). Both operands staged
// via glds-16B with XOR granule swizzle (rows are 128B -> unswizzled reads
// would be 16-way conflicted; swizzled = optimal 8-phase).
// cmode: 0 = bf16 row-major, 1 = f32 row-major, 2 = bf16 TRANSPOSED write
// to Cv with row-stride L_SEQ (fused V-transpose: Vt[d][L]).
// ---------------------------------------------------------------------------
__device__ inline void gemm128_body(const ushort_t* __restrict__ A,
                                    const ushort_t* __restrict__ Bt,
                                    void* __restrict__ Cv, int cmode,
                                    int m0, int n0) {
    constexpr int K = 1024, NOUT = 1024;
    __shared__ ushort_t As[128 * 64];   // [r][k], swizzled, 16 KB
    __shared__ ushort_t Bs[128 * 64];

    const int t = threadIdx.x, lane = t & 63, wave = t >> 6;
    const int l15 = lane & 15, quad = lane >> 4;
    const int mw = (wave >> 1) * 64, nw = (wave & 1) * 64;
    const int srow = lane >> 3;                       // 0..7 within 8-row slab
    const int sgr  = (lane & 7) ^ (lane >> 3);        // swizzled source granule
    const int swz  = l15 & 7;                         // read-side swizzle

    f32x4 acc[4][4] = {};

    for (int k0 = 0; k0 < K; k0 += 64) {
        #pragma unroll
        for (int i = 0; i < 4; ++i) {
            const int j = wave * 4 + i;               // 8-row slab id (0..15)
            load_lds16(A  + (size_t)(m0 + 8 * j + srow) * K + k0 + sgr * 8,
                       &As[8 * j * 64]);
            load_lds16(Bt + (size_t)(n0 + 8 * j + srow) * K + k0 + sgr * 8,
                       &Bs[8 * j * 64]);
        }
        __syncthreads();   // drains vmcnt (glds) before fragment reads

        #pragma unroll
        for (int kt = 0; kt < 2; ++kt) {
            bf16x8 af[4], bf[4];
            #pragma unroll
            for (int i = 0; i < 4; ++i) {
                af[i] = *(const bf16x8*)&As[(mw + i * 16 + l15) * 64
                                            + (((kt * 4 + quad) ^ swz) * 8)];
                bf[i] = *(const bf16x8*)&Bs[(nw + i * 16 + l15) * 64
                                            + (((kt * 4 + quad) ^ swz) * 8)];
            }
            #pragma unroll
            for (int mt = 0; mt < 4; ++mt)
                #pragma unroll
                for (int nt = 0; nt < 4; ++nt)
                    acc[mt][nt] = __builtin_amdgcn_mfma_f32_16x16x32_bf16(
                        af[mt], bf[nt], acc[mt][nt], 0, 0, 0);
        }
        __syncthreads();
    }

    if (cmode == 2) {
        // transposed write: Vt[col(d)][row(L)]; 4 acc regs = 4 consecutive L
        ushort_t* Vt = (ushort_t*)Cv;
        #pragma unroll
        for (int mt = 0; mt < 4; ++mt)
            #pragma unroll
            for (int nt = 0; nt < 4; ++nt) {
                int col  = n0 + nw + nt * 16 + l15;          // d
                int row0 = m0 + mw + mt * 16 + quad * 4;     // L (mult of 4)
                ushort_t pk[4] = {f2bf(acc[mt][nt][0]), f2bf(acc[mt][nt][1]),
                                  f2bf(acc[mt][nt][2]), f2bf(acc[mt][nt][3])};
                *(uint2*)&Vt[(size_t)col * L_SEQ + row0] = *(const uint2*)pk;
            }
        return;
    }

    ushort_t* Ch = (ushort_t*)Cv;
    float*    Cf = (float*)Cv;
    #pragma unroll
    for (int mt = 0; mt < 4; ++mt)
        #pragma unroll
        for (int nt = 0; nt < 4; ++nt)
            #pragma unroll
            for (int r = 0; r < 4; ++r) {
                int row = m0 + mw + mt * 16 + quad * 4 + r;
                int col = n0 + nw + nt * 16 + l15;
                if (cmode == 1) Cf[(size_t)row * NOUT + col] = acc[mt][nt][r];
                else            Ch[(size_t)row * NOUT + col] = f2bf(acc[mt][nt][r]);
            }
}

// qkv: 768 blocks. XCD-swizzled decode: n-tile = b&7 (constant per XCD under
// round-robin -> weight slice 768KB stays in that XCD's L2), y=(b>>3)&31,
// z=b>>8. z==2 writes Vt transposed (fused V-transpose).
__global__ __launch_bounds__(256) void qkv128(const ushort_t* __restrict__ xb,
                                              const ushort_t* __restrict__ wT,
                                              ushort_t* Qp, ushort_t* Kp, ushort_t* Vt) {
    const int b = blockIdx.x;
    const int n0 = (b & 7) * 128, m0 = ((b >> 3) & 31) * 128, z = b >> 8;
    const ushort_t* Bt = wT + (size_t)z * (DM * DM);
    if (z == 0)      gemm128_body(xb, Bt, Qp, 0, m0, n0);
    else if (z == 1) gemm128_body(xb, Bt, Kp, 0, m0, n0);
    else             gemm128_body(xb, Bt, Vt, 2, m0, n0);
}

__global__ __launch_bounds__(256) void ogemm128(const void* __restrict__ xdet,
                                                const ushort_t* __restrict__ An,
                                                const ushort_t* __restrict__ woT,
                                                void* __restrict__ C) {
    bool f32 = detect_f32((const ushort_t*)xdet);
    const int b = blockIdx.x;
    const int n0 = (b & 7) * 128, m0 = (b >> 3) * 128;
    gemm128_body(An, woT, C, f32 ? 1 : 0, m0, n0);
}

// ---------------------------------------------------------------------------
// Flash attention — EXACT R9 kernel (verified 115.8 us, passing).
// ---------------------------------------------------------------------------
__global__ __launch_bounds__(256) void attn_kernel(const ushort_t* __restrict__ Q,
                                                   const ushort_t* __restrict__ Kp,
                                                   const ushort_t* __restrict__ Vt,
                                                   ushort_t* __restrict__ O) {
    __shared__ ushort_t Ks[2][128 * 64];   // [kv][d], swizzled, 2 x 16 KB
    __shared__ ushort_t Vs[2][64 * 128];   // [d][kv], swizzled, 2 x 16 KB
    __shared__ ushort_t Pt[64 * 128];      // [q][kv], swizzled,     16 KB

    const int b    = blockIdx.x;               // 0..511
    const int h    = 2 * (b & 7) + ((b >> 3) & 1);
    const int bx   = b >> 4;                   // 0..31
    const int t    = threadIdx.x;
    const int lane = t & 63, wave = t >> 6;
    const int l15  = lane & 15, quad = lane >> 4;
    const float LOG2E  = 1.44269504f;
    const float slope2 = exp2f(-0.5f * (float)(h + 1)) * LOG2E;
    const float c0     = 0.125f * LOG2E;
    const float qd4f   = (float)(quad * 4);

    const int krow = lane >> 3, kgr = (lane & 7) ^ (lane >> 3);
    const int vsub = lane >> 4;
    const int swz = l15 & 7;

    auto stage_load = [&](int buf, int kv0) {
        #pragma unroll
        for (int i = 0; i < 4; ++i) {
            const int j = wave * 4 + i;
            const int r = 8 * j + krow;
            load_lds16(Kp + (size_t)(kv0 + r) * DM + h * HD + kgr * 8,
                       &Ks[buf][8 * j * 64]);
        }
        #pragma unroll
        for (int i = 0; i < 4; ++i) {
            const int j = wave * 4 + i;
            const int d = 4 * j + vsub;
            const int g = (lane & 15) ^ (4 * (j & 1) + vsub);
            load_lds16(Vt + (size_t)(h * HD + d) * L_SEQ + kv0 + g * 8,
                       &Vs[buf][4 * j * 128]);
        }
    };

    int par = 0;
    stage_load(0, 0);

    #pragma unroll
    for (int half = 0; half < 2; ++half) {
        const int qb = half ? bx : (63 - bx);
        const int q0 = qb * 64;
        const int qg = q0 + wave * 16 + l15;
        const float qf = (float)qg;

        bf16x8 bq[2];
        #pragma unroll
        for (int kt = 0; kt < 2; ++kt)
            bq[kt] = *(const bf16x8*)(Q + (size_t)qg * DM + h * HD + kt * 32 + quad * 8);

        f32x4 acc_o[4] = {};
        float m2 = -1e30f, l_r = 0.f;

        const int nst = (qb + 2) >> 1;
        for (int s = 0; s < nst; ++s) {
            const int kv0 = s * 128;
            __syncthreads();

            const int nkv0 = (s + 1 < nst) ? (s + 1) * 128 : 0;
            stage_load(par ^ 1, nkv0);

            f32x4 sacc[8];
            #pragma unroll
            for (int mt = 0; mt < 8; ++mt) sacc[mt] = (f32x4){0.f, 0.f, 0.f, 0.f};
            #pragma unroll
            for (int kt = 0; kt < 2; ++kt)
                #pragma unroll
                for (int mt = 0; mt < 8; ++mt) {
                    bf16x8 a = *(const bf16x8*)&Ks[par][(mt * 16 + l15) * 64
                                                        + (((kt * 4 + quad) ^ swz) * 8)];
                    sacc[mt] = __builtin_amdgcn_mfma_f32_16x16x32_bf16(a, bq[kt], sacc[mt], 0, 0, 0);
                }

            const bool diag = (kv0 + 128 > q0);
            const float off = slope2 * ((float)kv0 + qd4f - qf);
            #pragma unroll
            for (int mt = 0; mt < 8; ++mt)
                #pragma unroll
                for (int r = 0; r < 4; ++r) {
                    float kvl = (float)(mt * 16 + r);
                    float s2  = fmaf(sacc[mt][r], c0, fmaf(slope2, kvl, off));
                    if (diag) {
                        int kvg = kv0 + mt * 16 + quad * 4 + r;
                        s2 = (kvg <= qg) ? s2 : -1e30f;
                    }
                    sacc[mt][r] = s2;
                }

            float mx = sacc[0][0];
            #pragma unroll
            for (int mt = 0; mt < 8; ++mt)
                #pragma unroll
                for (int r = 0; r < 4; ++r) mx = fmaxf(mx, sacc[mt][r]);
            mx = fmaxf(mx, __shfl_xor(mx, 16));
            mx = fmaxf(mx, __shfl_xor(mx, 32));
            float m_new = fmaxf(m2, mx);
            float alpha = exp2f(m2 - m_new);
            m2 = m_new;

            float rs = 0.f;
            #pragma unroll
            for (int mt = 0; mt < 8; ++mt)
                #pragma unroll
                for (int r = 0; r < 4; ++r) {
                    float p = exp2f(sacc[mt][r] - m2);
                    sacc[mt][r] = p;
                    rs += p;
                }
            rs += __shfl_xor(rs, 16);
            rs += __shfl_xor(rs, 32);
            l_r = l_r * alpha + rs;

            float alpha_row[4];
            #pragma unroll
            for (int r = 0; r < 4; ++r) alpha_row[r] = __shfl(alpha, quad * 4 + r);
            #pragma unroll
            for (int nt = 0; nt < 4; ++nt)
                #pragma unroll
                for (int r = 0; r < 4; ++r) acc_o[nt][r] *= alpha_row[r];

            #pragma unroll
            for (int mt = 0; mt < 8; ++mt) {
                union { float f; unsigned u; } a0, a1, a2, a3;
                a0.f = sacc[mt][0]; a1.f = sacc[mt][1];
                a2.f = sacc[mt][2]; a3.f = sacc[mt][3];
                uint2 w;
                w.x = __builtin_amdgcn_perm(a1.u, a0.u, 0x07060302);
                w.y = __builtin_amdgcn_perm(a3.u, a2.u, 0x07060302);
                const int g = mt * 2 + (quad >> 1);
                *(uint2*)&Pt[(wave * 16 + l15) * 128
                             + ((g ^ swz) * 8 + (quad & 1) * 4)] = w;
            }
            __threadfence_block();

            #pragma unroll
            for (int kt = 0; kt < 4; ++kt) {
                bf16x8 a = *(const bf16x8*)&Pt[(wave * 16 + l15) * 128
                                               + (((kt * 4 + quad) ^ swz) * 8)];
                #pragma unroll
                for (int nt = 0; nt < 4; ++nt) {
                    bf16x8 bvv = *(const bf16x8*)&Vs[par][(nt * 16 + l15) * 128
                                                          + (((kt * 4 + quad) ^ swz) * 8)];
                    acc_o[nt] = __builtin_amdgcn_mfma_f32_16x16x32_bf16(a, bvv, acc_o[nt], 0, 0, 0);
                }
            }

            par ^= 1;
        }

        float linv[4];
        #pragma unroll
        for (int r = 0; r < 4; ++r) linv[r] = 1.0f / __shfl(l_r, quad * 4 + r);
        #pragma unroll
        for (int nt = 0; nt < 4; ++nt)
            #pragma unroll
            for (int r = 0; r < 4; ++r) {
                int row = q0 + wave * 16 + quad * 4 + r;
                O[(size_t)row * DM + h * HD + nt * 16 + l15] = f2bf(acc_o[nt][r] * linv[r]);
            }
    }
}

// ---------------------------------------------------------------------------
extern "C" void kernel_launch(void* const* d_in, const int* in_sizes, int n_in,
                              void* d_out, int out_size, void* d_ws, size_t ws_size,
                              hipStream_t stream) {
    const void* x  = d_in[0];
    const void* wq = d_in[1];
    const void* wk = d_in[2];
    const void* wv = d_in[3];
    const void* wo = d_in[4];

    const size_t SZ = (size_t)L_SEQ * DM;   // 4M elems
    const size_t WZ = (size_t)DM * DM;      // 1M elems
    ushort_t* xb = (ushort_t*)d_ws;         // 8 MB
    ushort_t* wT = xb + SZ;                 // 4 x 2 MB
    ushort_t* Qp = wT + 4 * WZ;             // 8 MB
    ushort_t* Kp = Qp + SZ;                 // 8 MB
    ushort_t* Vt = Kp + SZ;                 // 8 MB  -> total 40 MB
    ushort_t* An = xb;                      // xb dead after qkv -> safe alias

    convert_all<<<dim3(16, 16, 5), 256, 0, stream>>>(x, wq, wk, wv, wo, xb, wT);
    qkv128<<<768, 256, 0, stream>>>(xb, wT, Qp, Kp, Vt);
    attn_kernel<<<512, 256, 0, stream>>>(Qp, Kp, Vt, An);
    ogemm128<<<256, 256, 0, stream>>>(x, An, wT + 3 * WZ, d_out);
}